// Round 3
// baseline (1620.075 us; speedup 1.0000x reference)
//
#include <hip/hip_runtime.h>

typedef _Float16 f16;
typedef _Float16 f16x8 __attribute__((ext_vector_type(8)));
typedef float    f32x4 __attribute__((ext_vector_type(4)));
typedef unsigned int u32;

#define MFMA16(a,b,c) __builtin_amdgcn_mfma_f32_16x16x32_f16((a),(b),(c),0,0,0)

typedef __attribute__((address_space(1))) const u32 gu32;
typedef __attribute__((address_space(3))) u32 lu32;

static __device__ __forceinline__ float sigm(float x){ return 1.0f/(1.0f + __expf(-x)); }

// ---------------- workspace layout (bytes) ----------------
static constexpr size_t OFF_WSE_P  = 0;                                  // 4 MB
static constexpr size_t OFF_WSD_P  = OFF_WSE_P  + (size_t)8192*256*2;    // 4 MB
static constexpr size_t OFF_WIHE_P = OFF_WSD_P  + (size_t)8192*256*2;    // 512 KB
static constexpr size_t OFF_WIHD_P = OFF_WIHE_P + (size_t)256*1024*2;
static constexpr size_t OFF_WHHE_P = OFF_WIHD_P + (size_t)256*1024*2;
static constexpr size_t OFF_WHHD_P = OFF_WHHE_P + (size_t)256*1024*2;
static constexpr size_t OFF_W3E    = OFF_WHHD_P + (size_t)256*1024*2;
static constexpr size_t OFF_W3D    = OFF_W3E   + (size_t)3*1024*4;
static constexpr size_t OFF_W2WO   = OFF_W3D   + (size_t)3*1024*4;
static constexpr size_t OFF_BIASE  = OFF_W2WO  + (size_t)256*3*4;
static constexpr size_t OFF_BIASD  = OFF_BIASE + (size_t)1024*4;
static constexpr size_t OFF_B2WO   = OFF_BIASD + (size_t)1024*4;
static constexpr size_t OFF_SALE   = OFF_B2WO  + 256;
static constexpr size_t OFF_SALD   = OFF_SALE  + (size_t)5120*256*2;     // 2.6 MB
static constexpr size_t OFF_END    = OFF_SALD  + (size_t)25600*256*2;    // 13.1 MB

// ================= prep: pack weights (blocks 0-2559) + small folds (2560-2569)
// pack layout [kfg][ctg][lane][8]; element (k,n): k = kfg*32+(l>>4)*8+i, n = ctg*16+(l&15)
__global__ __launch_bounds__(256) void k_prep(
    const float* __restrict__ Wse, const float* __restrict__ Wsd,
    const float* __restrict__ Wih_e, const float* __restrict__ Wih_d,
    const float* __restrict__ Whh_e, const float* __restrict__ Whh_d,
    f16* pWse, f16* pWsd, f16* pWih_e, f16* pWih_d, f16* pWhh_e, f16* pWhh_d,
    const float* __restrict__ Wpe, const float* __restrict__ bpe,
    const float* __restrict__ bih_e, const float* __restrict__ bhh_e,
    const float* __restrict__ Wpd, const float* __restrict__ bpd,
    const float* __restrict__ bih_d, const float* __restrict__ bhh_d,
    const float* __restrict__ W2, const float* __restrict__ b2,
    const float* __restrict__ Wo, const float* __restrict__ bo,
    float* W3e, float* W3d, float* biasE, float* biasD, float* W2Wo, float* b2Wo)
{
  int blk = blockIdx.x;
  if (blk < 2560) {
    const float* W; f16* o; int N, base;
    if      (blk < 1024) { W=Wse;   o=pWse;   N=256;  base=0; }
    else if (blk < 2048) { W=Wsd;   o=pWsd;   N=256;  base=1024; }
    else if (blk < 2176) { W=Wih_e; o=pWih_e; N=1024; base=2048; }  // k rows 0..255 (sal part)
    else if (blk < 2304) { W=Wih_d; o=pWih_d; N=1024; base=2176; }
    else if (blk < 2432) { W=Whh_e; o=pWhh_e; N=1024; base=2304; }
    else                 { W=Whh_d; o=pWhh_d; N=1024; base=2432; }
    int tid = (blk - base)*256 + threadIdx.x;
    int l = tid & 63;
    int nct = N >> 4;
    int ctg = (tid >> 6) % nct;
    int kfg = (tid >> 6) / nct;
    int k0  = kfg*32 + ((l>>4)<<3);
    int col = ctg*16 + (l&15);
    f16x8 v;
#pragma unroll
    for (int i=0;i<8;++i) v[i] = (f16)W[(size_t)(k0+i)*N + col];
    *(f16x8*)(o + (size_t)tid*8) = v;
    return;
  }
  int bid = blk - 2560, tid = threadIdx.x;
  if (bid < 4) {
    int j = bid*256 + tid;
    float s0=0,s1=0,s2=0,sb=0;
    for (int m=0;m<256;++m) {
      float wv = Wih_e[(size_t)(256+m)*1024 + j];
      s0 += Wpe[m]*wv; s1 += Wpe[256+m]*wv; s2 += Wpe[512+m]*wv; sb += bpe[m]*wv;
    }
    W3e[j]=s0; W3e[1024+j]=s1; W3e[2048+j]=s2;
    biasE[j] = bih_e[j] + bhh_e[j] + sb;
  } else if (bid < 8) {
    int j = (bid-4)*256 + tid;
    float s0=0,s1=0,s2=0,sb=0;
    for (int m=0;m<256;++m) {
      float wv = Wih_d[(size_t)(256+m)*1024 + j];
      s0 += Wpd[m]*wv; s1 += Wpd[256+m]*wv; s2 += Wpd[512+m]*wv; sb += bpd[m]*wv;
    }
    W3d[j]=s0; W3d[1024+j]=s1; W3d[2048+j]=s2;
    biasD[j] = bih_d[j] + bhh_d[j] + sb;
  } else if (bid == 8) {
    int c = tid;
    float s0=0,s1=0,s2=0;
    for (int m=0;m<256;++m) {
      float wv = W2[(size_t)c*256+m];
      s0 += wv*Wo[m*3+0]; s1 += wv*Wo[m*3+1]; s2 += wv*Wo[m*3+2];
    }
    W2Wo[c*3+0]=s0; W2Wo[c*3+1]=s1; W2Wo[c*3+2]=s2;
  } else {
    if (tid < 192) {
      int j = tid >> 6, lane = tid & 63;
      float s = 0.f;
      for (int m=lane;m<256;m+=64) s += b2[m]*Wo[m*3+j];
#pragma unroll
      for (int msk=1;msk<64;msk<<=1) s += __shfl_xor(s, msk);
      if (lane==0) b2Wo[j] = s + bo[j];
    }
  }
}

// ============ big GEMM: sal' = A(f32, K=8192) @ Wp + bias -> f16 =============
// BM=128, BN=256(=full N), BK=64. 8 waves (2M x 4N), wave-tile 64x64.
// A reg-staged (fp32->f16 convert) -> LDS; B async global_load_lds (no convert).
__global__ __launch_bounds__(512) void k_gemm_big(
    const float* __restrict__ A0, const f16* __restrict__ W0,
    const float* __restrict__ b0, f16* __restrict__ o0, int nb0,
    const float* __restrict__ A1, const f16* __restrict__ W1,
    const float* __restrict__ b1, f16* __restrict__ o1)
{
  __shared__ f16 aBuf[2][128*64];   // 16 KB each, swizzled (16B slot ^= row&7)
  __shared__ f16 bBuf[2][64*256];   // 32 KB each, packed-frag linear order
  const int tid = threadIdx.x, l = tid & 63, w = tid >> 6;
  const int li = l & 15, hi = l >> 4;
  const int wr = w >> 2, wc = w & 3;
  const int bx = blockIdx.x;
  const float* Ap; const f16* Wp; const float* bias; f16* out; int rblk;
  if (bx < nb0) { Ap=A0; Wp=W0; bias=b0; out=o0; rblk = bx*128; }
  else          { Ap=A1; Wp=W1; bias=b1; out=o1; rblk = (bx-nb0)*128; }

  f32x4 acc[4][4];
#pragma unroll
  for (int a=0;a<4;++a)
#pragma unroll
    for (int b=0;b<4;++b) acc[a][b] = (f32x4){0.f,0.f,0.f,0.f};

  const int arow = tid >> 2, kseg = tid & 3;           // A stage: 128 rows x 4 segs
  const float* Arow = Ap + (size_t)(rblk + arow)*8192 + kseg*16;

  float4 f0,f1,f2,f3;
#define LOADA(ti_) { const float* Aq = Arow + (ti_)*64;                       \
    f0 = *(const float4*)Aq;     f1 = *(const float4*)(Aq+4);                 \
    f2 = *(const float4*)(Aq+8); f3 = *(const float4*)(Aq+12); }
#define STAGEB(ti_, nb_) { const f16* bch = Wp + (size_t)(ti_)*16384;         \
    _Pragma("unroll")                                                         \
    for (int is=0; is<4; ++is) {                                              \
      const f16* g = bch + w*2048 + is*512 + l*8;                             \
      f16* s = &bBuf[nb_][w*2048 + is*512];                                   \
      __builtin_amdgcn_global_load_lds((gu32*)g, (lu32*)s, 16, 0, 0);         \
    } }

  STAGEB(0, 0);
  LOADA(0);

  for (int ti = 0; ti < 128; ++ti) {
    const int buf = ti & 1;
    f16x8 w0, w1;   // convert (compiler's wait on f-regs also drains our B issues)
    w0[0]=(f16)f0.x; w0[1]=(f16)f0.y; w0[2]=(f16)f0.z; w0[3]=(f16)f0.w;
    w0[4]=(f16)f1.x; w0[5]=(f16)f1.y; w0[6]=(f16)f1.z; w0[7]=(f16)f1.w;
    w1[0]=(f16)f2.x; w1[1]=(f16)f2.y; w1[2]=(f16)f2.z; w1[3]=(f16)f2.w;
    w1[4]=(f16)f3.x; w1[5]=(f16)f3.y; w1[6]=(f16)f3.z; w1[7]=(f16)f3.w;
    __syncthreads();      // compute(ti-1) readers done with both bufs
    *(f16x8*)&aBuf[buf][arow*64 + ((kseg*2    ) ^ (arow&7))*8] = w0;
    *(f16x8*)&aBuf[buf][arow*64 + ((kseg*2 + 1) ^ (arow&7))*8] = w1;
    if (ti + 1 < 128) { STAGEB(ti+1, buf^1); LOADA(ti+1); }
    __syncthreads();      // staging visible (every wave drained its own B before here)
#pragma unroll
    for (int kf = 0; kf < 2; ++kf) {
      f16x8 afr[4], bfr[4];
#pragma unroll
      for (int rt=0; rt<4; ++rt) {
        int row = wr*64 + rt*16 + li;
        afr[rt] = *(f16x8*)&aBuf[buf][row*64 + (((kf*4) + hi) ^ (row&7))*8];
      }
#pragma unroll
      for (int ct=0; ct<4; ++ct) {
        int ctg = wc*4 + ct;
        bfr[ct] = *(f16x8*)&bBuf[buf][(kf*16 + ctg)*512 + l*8];
      }
#pragma unroll
      for (int rt=0; rt<4; ++rt)
#pragma unroll
        for (int ct=0; ct<4; ++ct)
          acc[rt][ct] = MFMA16(afr[rt], bfr[ct], acc[rt][ct]);
    }
  }
#undef LOADA
#undef STAGEB
  // epilogue: D map col=l&15, row=4*(l>>4)+i
#pragma unroll
  for (int ct=0; ct<4; ++ct) {
    int col = wc*64 + ct*16 + li;
    float bv = bias[col];
#pragma unroll
    for (int rt=0; rt<4; ++rt)
#pragma unroll
      for (int i=0;i<4;++i) {
        int r = rblk + wr*64 + rt*16 + hi*4 + i;
        out[(size_t)r*256 + col] = (f16)(acc[rt][ct][i] + bv);
      }
  }
}

// ================= fused recurrent kernel: encoder(5) then decoder(25) ======
// 64 blocks x 16 rows, 512 threads (8 waves). wave w owns h-cols [w*32,+32):
// ctg = q*16 + w*2 + j -> gate quadruples lane-local.
// per step: acc = x_t @ Wih_top + h @ Whh (both MFMA), gates + pos*W3 + bias in regs.
__global__ __launch_bounds__(512) void k_rnn(
    const f16* __restrict__ sal_e,   // (B*5, 256)
    const f16* __restrict__ sal_d,   // (B*25, 256)
    const f16* __restrict__ Wih_e_p, const f16* __restrict__ Whh_e_p,
    const f16* __restrict__ Wih_d_p, const f16* __restrict__ Whh_d_p,
    const float* __restrict__ W3e, const float* __restrict__ W3d,
    const float* __restrict__ biasE, const float* __restrict__ biasD,
    const float* __restrict__ enc_pos, const float* __restrict__ dec_pos,
    const float* __restrict__ W2Wo, const float* __restrict__ b2Wo,
    float* __restrict__ out)         // (B,25,3)
{
  __shared__ f16 hLDS[16*256];       // swizzled (16B slot ^= row&7)
  __shared__ f16 xLDS[2][16*256];
  __shared__ float posS[2][16][4];
  __shared__ float dpart[8][16][3];
  const int tid = threadIdx.x, l = tid & 63, w = tid >> 6;
  const int li = l & 15, hi = l >> 4;
  const int rb = blockIdx.x*16;
  const int sr = tid >> 5, sseg = tid & 31;   // x staging: row, 16B slot

  for (int i=tid;i<2048;i+=512) ((u32*)hLDS)[i]=0u;
  float c_st[2][4];
#pragma unroll
  for (int j=0;j<2;++j)
#pragma unroll
    for (int i=0;i<4;++i) c_st[j][i]=0.f;

  // hoisted per-thread constants (encoder set)
  float w3r[2][4][3], bvr[2][4];
#pragma unroll
  for (int j=0;j<2;++j) {
    int hc = w*32 + j*16 + li;
#pragma unroll
    for (int q=0;q<4;++q) {
      int gc = q*256 + hc;
      w3r[j][q][0]=W3e[gc]; w3r[j][q][1]=W3e[1024+gc]; w3r[j][q][2]=W3e[2048+gc];
      bvr[j][q]=biasE[gc];
    }
  }

#define MFMA_PHASE(XB, WIH, WHH)                                              \
  f32x4 acc[4][2];                                                            \
  _Pragma("unroll")                                                           \
  for (int q=0;q<4;++q){ acc[q][0]=(f32x4){0,0,0,0}; acc[q][1]=(f32x4){0,0,0,0}; } \
  _Pragma("unroll")                                                           \
  for (int kf=0;kf<8;++kf) {                                                  \
    f16x8 ax = *(f16x8*)&xLDS[XB][li*256 + (((kf*4)+hi) ^ (li&7))*8];         \
    f16x8 ah = *(f16x8*)&hLDS[li*256 + (((kf*4)+hi) ^ (li&7))*8];             \
    _Pragma("unroll")                                                         \
    for (int q=0;q<4;++q)                                                     \
      _Pragma("unroll")                                                       \
      for (int j=0;j<2;++j) {                                                 \
        int ctg = q*16 + w*2 + j;                                             \
        f16x8 bi = *(const f16x8*)(WIH + ((size_t)(kf*64+ctg)*64 + l)*8);     \
        f16x8 bh = *(const f16x8*)(WHH + ((size_t)(kf*64+ctg)*64 + l)*8);     \
        acc[q][j] = MFMA16(ax, bi, acc[q][j]);                                \
        acc[q][j] = MFMA16(ah, bh, acc[q][j]);                                \
      }                                                                       \
  }

  // ---------------- encoder ----------------
  f16x8 xreg = *(const f16x8*)(sal_e + ((size_t)(rb+sr)*5 + 0)*256 + sseg*8);
  for (int t=0;t<5;++t) {
    const int xb = t & 1;
    *(f16x8*)&xLDS[xb][sr*256 + (sseg ^ (sr&7))*8] = xreg;
    if (t+1 < 5) xreg = *(const f16x8*)(sal_e + ((size_t)(rb+sr)*5 + t+1)*256 + sseg*8);
    float pp[4][3];
#pragma unroll
    for (int i=0;i<4;++i) {
      int grow = rb + hi*4 + i;
      pp[i][0]=enc_pos[(grow*5+t)*3+0]; pp[i][1]=enc_pos[(grow*5+t)*3+1]; pp[i][2]=enc_pos[(grow*5+t)*3+2];
    }
    __syncthreads();          // x tile + (t==0) init visible; prev readers done
    MFMA_PHASE(xb, Wih_e_p, Whh_e_p)
    __syncthreads();          // hLDS readers done -> safe to rewrite
#pragma unroll
    for (int i=0;i<4;++i) {
      int r = hi*4 + i;
#pragma unroll
      for (int j=0;j<2;++j) {
        int hc = w*32 + j*16 + li;
        float gq[4];
#pragma unroll
        for (int q=0;q<4;++q)
          gq[q] = acc[q][j][i] + bvr[j][q]
                + pp[i][0]*w3r[j][q][0] + pp[i][1]*w3r[j][q][1] + pp[i][2]*w3r[j][q][2];
        float cn = sigm(gq[1])*c_st[j][i] + sigm(gq[0])*tanhf(gq[2]);
        c_st[j][i] = cn;
        float h = sigm(gq[3])*tanhf(cn);
        hLDS[r*256 + (((hc>>3) ^ (r&7))<<3) + (hc&7)] = (f16)h;
      }
    }
  }

  // ---------------- switch to decoder constants ----------------
  float w2r[2][3];
#pragma unroll
  for (int j=0;j<2;++j) {
    int hc = w*32 + j*16 + li;
#pragma unroll
    for (int q=0;q<4;++q) {
      int gc = q*256 + hc;
      w3r[j][q][0]=W3d[gc]; w3r[j][q][1]=W3d[1024+gc]; w3r[j][q][2]=W3d[2048+gc];
      bvr[j][q]=biasD[gc];
    }
    w2r[j][0]=W2Wo[hc*3+0]; w2r[j][1]=W2Wo[hc*3+1]; w2r[j][2]=W2Wo[hc*3+2];
  }
  if (tid < 48) { int r=tid/3, k=tid-3*(tid/3); posS[0][r][k] = dec_pos[(size_t)(rb+r)*3 + k]; }
  const float b2w0 = b2Wo[0], b2w1 = b2Wo[1], b2w2 = b2Wo[2];
  xreg = *(const f16x8*)(sal_d + ((size_t)(rb+sr)*25 + 0)*256 + sseg*8);

  // ---------------- decoder ----------------
  int cur = 0;
  for (int t=0;t<25;++t) {
    const int xb = t & 1;
    *(f16x8*)&xLDS[xb][sr*256 + (sseg ^ (sr&7))*8] = xreg;
    if (t+1 < 25) xreg = *(const f16x8*)(sal_d + ((size_t)(rb+sr)*25 + t+1)*256 + sseg*8);
    __syncthreads();          // x tile + posS[cur] + hLDS visible
    MFMA_PHASE(xb, Wih_d_p, Whh_d_p)
    __syncthreads();          // hLDS readers done
    float dpar[4][3];
#pragma unroll
    for (int i=0;i<4;++i){ dpar[i][0]=0.f; dpar[i][1]=0.f; dpar[i][2]=0.f; }
#pragma unroll
    for (int i=0;i<4;++i) {
      int r = hi*4 + i;
      float p0 = posS[cur][r][0], p1 = posS[cur][r][1], p2 = posS[cur][r][2];
#pragma unroll
      for (int j=0;j<2;++j) {
        int hc = w*32 + j*16 + li;
        float gq[4];
#pragma unroll
        for (int q=0;q<4;++q)
          gq[q] = acc[q][j][i] + bvr[j][q]
                + p0*w3r[j][q][0] + p1*w3r[j][q][1] + p2*w3r[j][q][2];
        float cn = sigm(gq[1])*c_st[j][i] + sigm(gq[0])*tanhf(gq[2]);
        c_st[j][i] = cn;
        float h = sigm(gq[3])*tanhf(cn);
        hLDS[r*256 + (((hc>>3) ^ (r&7))<<3) + (hc&7)] = (f16)h;
        dpar[i][0] += h*w2r[j][0];
        dpar[i][1] += h*w2r[j][1];
        dpar[i][2] += h*w2r[j][2];
      }
    }
#pragma unroll
    for (int m=1;m<16;m<<=1)
#pragma unroll
      for (int i=0;i<4;++i) {
        dpar[i][0] += __shfl_xor(dpar[i][0], m);
        dpar[i][1] += __shfl_xor(dpar[i][1], m);
        dpar[i][2] += __shfl_xor(dpar[i][2], m);
      }
    if (li==0) {
#pragma unroll
      for (int i=0;i<4;++i) {
        int r = hi*4 + i;
        dpart[w][r][0]=dpar[i][0]; dpart[w][r][1]=dpar[i][1]; dpart[w][r][2]=dpar[i][2];
      }
    }
    __syncthreads();
    if (tid < 16) {
      int r = tid;
      float d0=b2w0, d1=b2w1, d2=b2w2;
#pragma unroll
      for (int ww=0;ww<8;++ww){ d0+=dpart[ww][r][0]; d1+=dpart[ww][r][1]; d2+=dpart[ww][r][2]; }
      float p0 = posS[cur][r][0]+d0, p1 = posS[cur][r][1]+d1, p2 = posS[cur][r][2]+d2;
      float inv = 1.0f/sqrtf(p0*p0+p1*p1+p2*p2);
      p0*=inv; p1*=inv; p2*=inv;
      posS[cur^1][r][0]=p0; posS[cur^1][r][1]=p1; posS[cur^1][r][2]=p2;
      float* o = out + (size_t)(rb+r)*75 + t*3;
      o[0]=p0; o[1]=p1; o[2]=p2;
    }
    cur ^= 1;
    // next iteration's first __syncthreads() orders posS/hLDS for readers
  }
#undef MFMA_PHASE
}

// ================= launch =================
extern "C" void kernel_launch(void* const* d_in, const int* in_sizes, int n_in,
                              void* d_out, int out_size, void* d_ws, size_t ws_size,
                              hipStream_t stream)
{
  const float* enc_pos = (const float*)d_in[0];
  const float* enc_sal = (const float*)d_in[1];
  const float* dec_pos = (const float*)d_in[2];
  const float* dec_sal = (const float*)d_in[3];
  const float* Wpe  = (const float*)d_in[4];
  const float* bpe  = (const float*)d_in[5];
  const float* Wse  = (const float*)d_in[6];
  const float* bse  = (const float*)d_in[7];
  const float* Wih_e= (const float*)d_in[8];
  const float* Whh_e= (const float*)d_in[9];
  const float* bih_e= (const float*)d_in[10];
  const float* bhh_e= (const float*)d_in[11];
  const float* Wih_d= (const float*)d_in[12];
  const float* Whh_d= (const float*)d_in[13];
  const float* bih_d= (const float*)d_in[14];
  const float* bhh_d= (const float*)d_in[15];
  const float* Wpd  = (const float*)d_in[16];
  const float* bpd  = (const float*)d_in[17];
  const float* Wsd  = (const float*)d_in[18];
  const float* bsd  = (const float*)d_in[19];
  const float* W2   = (const float*)d_in[20];
  const float* b2   = (const float*)d_in[21];
  const float* Wo   = (const float*)d_in[22];
  const float* bo   = (const float*)d_in[23];

  char* ws = (char*)d_ws;
  f16* pWse   = (f16*)(ws + OFF_WSE_P);
  f16* pWsd   = (f16*)(ws + OFF_WSD_P);
  f16* pWih_e = (f16*)(ws + OFF_WIHE_P);
  f16* pWih_d = (f16*)(ws + OFF_WIHD_P);
  f16* pWhh_e = (f16*)(ws + OFF_WHHE_P);
  f16* pWhh_d = (f16*)(ws + OFF_WHHD_P);
  float* W3e  = (float*)(ws + OFF_W3E);
  float* W3d  = (float*)(ws + OFF_W3D);
  float* W2WoP= (float*)(ws + OFF_W2WO);
  float* biasE= (float*)(ws + OFF_BIASE);
  float* biasD= (float*)(ws + OFF_BIASD);
  float* b2WoP= (float*)(ws + OFF_B2WO);
  f16* sal_e  = (f16*)(ws + OFF_SALE);
  f16* sal_d  = (f16*)(ws + OFF_SALD);
  float* out  = (float*)d_out;

  hipLaunchKernelGGL(k_prep, dim3(2570), dim3(256), 0, stream,
                     Wse, Wsd, Wih_e, Wih_d, Whh_e, Whh_d,
                     pWse, pWsd, pWih_e, pWih_d, pWhh_e, pWhh_d,
                     Wpe, bpe, bih_e, bhh_e, Wpd, bpd, bih_d, bhh_d,
                     W2, b2, Wo, bo,
                     W3e, W3d, biasE, biasD, W2WoP, b2WoP);
  // sal projections: enc tiles [0,40), dec tiles [40,240)
  hipLaunchKernelGGL(k_gemm_big, dim3(240), dim3(512), 0, stream,
                     enc_sal, pWse, bse, sal_e, 40,
                     dec_sal, pWsd, bsd, sal_d);
  // fused encoder+decoder recurrence
  hipLaunchKernelGGL(k_rnn, dim3(64), dim3(512), 0, stream,
                     sal_e, sal_d, pWih_e, pWhh_e, pWih_d, pWhh_d,
                     W3e, W3d, biasE, biasD, enc_pos, dec_pos,
                     W2WoP, b2WoP, out);
}

// Round 4
// 808.726 us; speedup vs baseline: 2.0032x; 2.0032x over previous
//
#include <hip/hip_runtime.h>

typedef _Float16 f16;
typedef _Float16 f16x4 __attribute__((ext_vector_type(4)));
typedef _Float16 f16x8 __attribute__((ext_vector_type(8)));
typedef float    f32x4 __attribute__((ext_vector_type(4)));
typedef unsigned int u32;

#define MFMA16(a,b,c) __builtin_amdgcn_mfma_f32_16x16x32_f16((a),(b),(c),0,0,0)

typedef __attribute__((address_space(1))) const u32 gu32;
typedef __attribute__((address_space(3))) u32 lu32;

static __device__ __forceinline__ float sigm(float x){ return 1.0f/(1.0f + __expf(-x)); }

// ---------------- workspace layout (bytes) ----------------
static constexpr size_t OFF_WSE_P  = 0;                                  // 4 MB
static constexpr size_t OFF_WSD_P  = OFF_WSE_P  + (size_t)8192*256*2;    // 4 MB
static constexpr size_t OFF_WIHE_P = OFF_WSD_P  + (size_t)8192*256*2;    // 512 KB
static constexpr size_t OFF_WIHD_P = OFF_WIHE_P + (size_t)256*1024*2;
static constexpr size_t OFF_WHHE_P = OFF_WIHD_P + (size_t)256*1024*2;
static constexpr size_t OFF_WHHD_P = OFF_WHHE_P + (size_t)256*1024*2;
static constexpr size_t OFF_W3E    = OFF_WHHD_P + (size_t)256*1024*2;
static constexpr size_t OFF_W3D    = OFF_W3E   + (size_t)3*1024*4;
static constexpr size_t OFF_W2WO   = OFF_W3D   + (size_t)3*1024*4;
static constexpr size_t OFF_BIASE  = OFF_W2WO  + (size_t)256*3*4;
static constexpr size_t OFF_BIASD  = OFF_BIASE + (size_t)1024*4;
static constexpr size_t OFF_B2WO   = OFF_BIASD + (size_t)1024*4;
static constexpr size_t OFF_SALE   = OFF_B2WO  + 256;
static constexpr size_t OFF_SALD   = OFF_SALE  + (size_t)5120*256*2;     // 2.6 MB
static constexpr size_t OFF_PREGE  = OFF_SALD  + (size_t)25600*256*2;    // 13.1 MB
static constexpr size_t OFF_PREGD  = OFF_PREGE + (size_t)5120*1024*2;    // 10.5 MB
static constexpr size_t OFF_END    = OFF_PREGD + (size_t)25600*1024*2;   // 52.4 MB

// ================= prep: pack weights (blocks 0-2559) + small folds (2560-2569)
// pack layout [kfg][ctg][lane][8]; element (k,n): k = kfg*32+(l>>4)*8+i, n = ctg*16+(l&15)
__global__ __launch_bounds__(256) void k_prep(
    const float* __restrict__ Wse, const float* __restrict__ Wsd,
    const float* __restrict__ Wih_e, const float* __restrict__ Wih_d,
    const float* __restrict__ Whh_e, const float* __restrict__ Whh_d,
    f16* pWse, f16* pWsd, f16* pWih_e, f16* pWih_d, f16* pWhh_e, f16* pWhh_d,
    const float* __restrict__ Wpe, const float* __restrict__ bpe,
    const float* __restrict__ bih_e, const float* __restrict__ bhh_e,
    const float* __restrict__ Wpd, const float* __restrict__ bpd,
    const float* __restrict__ bih_d, const float* __restrict__ bhh_d,
    const float* __restrict__ W2, const float* __restrict__ b2,
    const float* __restrict__ Wo, const float* __restrict__ bo,
    float* W3e, float* W3d, float* biasE, float* biasD, float* W2Wo, float* b2Wo)
{
  int blk = blockIdx.x;
  if (blk < 2560) {
    const float* W; f16* o; int N, base;
    if      (blk < 1024) { W=Wse;   o=pWse;   N=256;  base=0; }
    else if (blk < 2048) { W=Wsd;   o=pWsd;   N=256;  base=1024; }
    else if (blk < 2176) { W=Wih_e; o=pWih_e; N=1024; base=2048; }  // k rows 0..255 (sal part)
    else if (blk < 2304) { W=Wih_d; o=pWih_d; N=1024; base=2176; }
    else if (blk < 2432) { W=Whh_e; o=pWhh_e; N=1024; base=2304; }
    else                 { W=Whh_d; o=pWhh_d; N=1024; base=2432; }
    int tid = (blk - base)*256 + threadIdx.x;
    int l = tid & 63;
    int nct = N >> 4;
    int ctg = (tid >> 6) % nct;
    int kfg = (tid >> 6) / nct;
    int k0  = kfg*32 + ((l>>4)<<3);
    int col = ctg*16 + (l&15);
    f16x8 v;
#pragma unroll
    for (int i=0;i<8;++i) v[i] = (f16)W[(size_t)(k0+i)*N + col];
    *(f16x8*)(o + (size_t)tid*8) = v;
    return;
  }
  int bid = blk - 2560, tid = threadIdx.x;
  if (bid < 4) {
    int j = bid*256 + tid;
    float s0=0,s1=0,s2=0,sb=0;
    for (int m=0;m<256;++m) {
      float wv = Wih_e[(size_t)(256+m)*1024 + j];
      s0 += Wpe[m]*wv; s1 += Wpe[256+m]*wv; s2 += Wpe[512+m]*wv; sb += bpe[m]*wv;
    }
    W3e[j]=s0; W3e[1024+j]=s1; W3e[2048+j]=s2;
    biasE[j] = bih_e[j] + bhh_e[j] + sb;
  } else if (bid < 8) {
    int j = (bid-4)*256 + tid;
    float s0=0,s1=0,s2=0,sb=0;
    for (int m=0;m<256;++m) {
      float wv = Wih_d[(size_t)(256+m)*1024 + j];
      s0 += Wpd[m]*wv; s1 += Wpd[256+m]*wv; s2 += Wpd[512+m]*wv; sb += bpd[m]*wv;
    }
    W3d[j]=s0; W3d[1024+j]=s1; W3d[2048+j]=s2;
    biasD[j] = bih_d[j] + bhh_d[j] + sb;
  } else if (bid == 8) {
    int c = tid;
    float s0=0,s1=0,s2=0;
    for (int m=0;m<256;++m) {
      float wv = W2[(size_t)c*256+m];
      s0 += wv*Wo[m*3+0]; s1 += wv*Wo[m*3+1]; s2 += wv*Wo[m*3+2];
    }
    W2Wo[c*3+0]=s0; W2Wo[c*3+1]=s1; W2Wo[c*3+2]=s2;
  } else {
    if (tid < 192) {
      int j = tid >> 6, lane = tid & 63;
      float s = 0.f;
      for (int m=lane;m<256;m+=64) s += b2[m]*Wo[m*3+j];
#pragma unroll
      for (int msk=1;msk<64;msk<<=1) s += __shfl_xor(s, msk);
      if (lane==0) b2Wo[j] = s + bo[j];
    }
  }
}

// ============ big GEMM: sal' = A(f32, K=8192) @ Wp + bias -> f16 =============
// BM=128, BN=256(=full N), BK=64. 8 waves (2M x 4N), wave-tile 64x64.
// A reg-staged (fp32->f16 convert) -> LDS; B async global_load_lds (no convert).
__global__ __launch_bounds__(512) void k_gemm_big(
    const float* __restrict__ A0, const f16* __restrict__ W0,
    const float* __restrict__ b0, f16* __restrict__ o0, int nb0,
    const float* __restrict__ A1, const f16* __restrict__ W1,
    const float* __restrict__ b1, f16* __restrict__ o1)
{
  __shared__ f16 aBuf[2][128*64];   // 16 KB each, swizzled (16B slot ^= row&7)
  __shared__ f16 bBuf[2][64*256];   // 32 KB each, packed-frag linear order
  const int tid = threadIdx.x, l = tid & 63, w = tid >> 6;
  const int li = l & 15, hi = l >> 4;
  const int wr = w >> 2, wc = w & 3;
  const int bx = blockIdx.x;
  const float* Ap; const f16* Wp; const float* bias; f16* out; int rblk;
  if (bx < nb0) { Ap=A0; Wp=W0; bias=b0; out=o0; rblk = bx*128; }
  else          { Ap=A1; Wp=W1; bias=b1; out=o1; rblk = (bx-nb0)*128; }

  f32x4 acc[4][4];
#pragma unroll
  for (int a=0;a<4;++a)
#pragma unroll
    for (int b=0;b<4;++b) acc[a][b] = (f32x4){0.f,0.f,0.f,0.f};

  const int arow = tid >> 2, kseg = tid & 3;           // A stage: 128 rows x 4 segs
  const float* Arow = Ap + (size_t)(rblk + arow)*8192 + kseg*16;

  float4 f0,f1,f2,f3;
#define LOADA(ti_) { const float* Aq = Arow + (ti_)*64;                       \
    f0 = *(const float4*)Aq;     f1 = *(const float4*)(Aq+4);                 \
    f2 = *(const float4*)(Aq+8); f3 = *(const float4*)(Aq+12); }
#define STAGEB(ti_, nb_) { const f16* bch = Wp + (size_t)(ti_)*16384;         \
    _Pragma("unroll")                                                         \
    for (int is=0; is<4; ++is) {                                              \
      const f16* g = bch + w*2048 + is*512 + l*8;                             \
      f16* s = &bBuf[nb_][w*2048 + is*512];                                   \
      __builtin_amdgcn_global_load_lds((gu32*)g, (lu32*)s, 16, 0, 0);         \
    } }

  STAGEB(0, 0);
  LOADA(0);

  for (int ti = 0; ti < 128; ++ti) {
    const int buf = ti & 1;
    f16x8 w0, w1;
    w0[0]=(f16)f0.x; w0[1]=(f16)f0.y; w0[2]=(f16)f0.z; w0[3]=(f16)f0.w;
    w0[4]=(f16)f1.x; w0[5]=(f16)f1.y; w0[6]=(f16)f1.z; w0[7]=(f16)f1.w;
    w1[0]=(f16)f2.x; w1[1]=(f16)f2.y; w1[2]=(f16)f2.z; w1[3]=(f16)f2.w;
    w1[4]=(f16)f3.x; w1[5]=(f16)f3.y; w1[6]=(f16)f3.z; w1[7]=(f16)f3.w;
    __syncthreads();      // compute(ti-1) readers done with both bufs
    *(f16x8*)&aBuf[buf][arow*64 + ((kseg*2    ) ^ (arow&7))*8] = w0;
    *(f16x8*)&aBuf[buf][arow*64 + ((kseg*2 + 1) ^ (arow&7))*8] = w1;
    if (ti + 1 < 128) { STAGEB(ti+1, buf^1); LOADA(ti+1); }
    __syncthreads();      // staging visible
#pragma unroll
    for (int kf = 0; kf < 2; ++kf) {
      f16x8 afr[4], bfr[4];
#pragma unroll
      for (int rt=0; rt<4; ++rt) {
        int row = wr*64 + rt*16 + li;
        afr[rt] = *(f16x8*)&aBuf[buf][row*64 + (((kf*4) + hi) ^ (row&7))*8];
      }
#pragma unroll
      for (int ct=0; ct<4; ++ct) {
        int ctg = wc*4 + ct;
        bfr[ct] = *(f16x8*)&bBuf[buf][(kf*16 + ctg)*512 + l*8];
      }
#pragma unroll
      for (int rt=0; rt<4; ++rt)
#pragma unroll
        for (int ct=0; ct<4; ++ct)
          acc[rt][ct] = MFMA16(afr[rt], bfr[ct], acc[rt][ct]);
    }
  }
#undef LOADA
#undef STAGEB
  // epilogue: D map col=l&15, row=4*(l>>4)+i
#pragma unroll
  for (int ct=0; ct<4; ++ct) {
    int col = wc*64 + ct*16 + li;
    float bv = bias[col];
#pragma unroll
    for (int rt=0; rt<4; ++rt)
#pragma unroll
      for (int i=0;i<4;++i) {
        int r = rblk + wr*64 + rt*16 + hi*4 + i;
        out[(size_t)r*256 + col] = (f16)(acc[rt][ct][i] + bv);
      }
  }
}

// ============ pre-gate GEMM over t-major row permutation ====================
// rows r' = t*1024 + b (t = r'>>10, b = r'&1023); A-source row = b*T + t.
// out = fragment-order preg: P[b_blk][t][ctg(64)][lane(64)][i(4)] f16,
// so the RNN can C-init its accumulators with dense dwordx2 loads.
// 4 waves, tile 64 rows x 256 cols, K=256, bias folded.
__global__ __launch_bounds__(256) void k_pregate(
    const f16* __restrict__ A0, const f16* __restrict__ W0p,
    const float* __restrict__ bias0, f16* __restrict__ P0, int nb0, int T0,
    const f16* __restrict__ A1, const f16* __restrict__ W1p,
    const float* __restrict__ bias1, f16* __restrict__ P1, int T1)
{
  __shared__ f16 aLDS[2][64*64];
  const int tid = threadIdx.x, l = tid & 63, w = tid >> 6;
  const int li = l & 15, hi = l >> 4;
  const int bx = blockIdx.x;
  const f16* Ap; const f16* Wp; const float* bias; f16* P; int rblk, T;
  if (bx < nb0) { Ap=A0; Wp=W0p; bias=bias0; P=P0; rblk=bx*64;        T=T0; }
  else          { Ap=A1; Wp=W1p; bias=bias1; P=P1; rblk=(bx-nb0)*64;  T=T1; }
  const int cbase = blockIdx.y * 256;

  f32x4 acc[4][4];
#pragma unroll
  for (int a=0;a<4;++a)
#pragma unroll
    for (int b=0;b<4;++b) acc[a][b] = (f32x4){0.f,0.f,0.f,0.f};

  const int srow = tid >> 2, kseg = tid & 3;
  const int rp = rblk + srow;
  const f16* Arow = Ap + ((size_t)(rp & 1023)*T + (rp >> 10))*256 + kseg*16;

  f16x8 v0 = *(const f16x8*)(Arow), v1 = *(const f16x8*)(Arow + 8);
  for (int kk = 0; kk < 256; kk += 64) {
    const int buf = (kk>>6)&1;
    __syncthreads();
    *(f16x8*)&aLDS[buf][srow*64 + ((kseg*2    ) ^ (srow&7))*8] = v0;
    *(f16x8*)&aLDS[buf][srow*64 + ((kseg*2 + 1) ^ (srow&7))*8] = v1;
    const int kn = (kk + 64 < 256) ? (kk + 64) : kk;
    v0 = *(const f16x8*)(Arow + kn);
    v1 = *(const f16x8*)(Arow + kn + 8);
    __syncthreads();
    const int kfg0 = kk >> 5;
#pragma unroll
    for (int kf = 0; kf < 2; ++kf) {
      f16x8 afr[4], bfr[4];
#pragma unroll
      for (int rt=0; rt<4; ++rt) {
        int row = rt*16 + li;
        afr[rt] = *(f16x8*)&aLDS[buf][row*64 + (((kf*4) + hi) ^ (row&7))*8];
      }
#pragma unroll
      for (int ct=0; ct<4; ++ct) {
        int ctg = (cbase>>4) + w*4 + ct;
        bfr[ct] = *(const f16x8*)(Wp + ((size_t)((kfg0+kf)*64 + ctg)*64 + l)*8);
      }
#pragma unroll
      for (int rt=0; rt<4; ++rt)
#pragma unroll
        for (int ct=0; ct<4; ++ct)
          acc[rt][ct] = MFMA16(afr[rt], bfr[ct], acc[rt][ct]);
    }
  }
  // epilogue: fragment-order store. t uniform per block (tiles don't cross t).
  const int t = rblk >> 10;
  const int bblk0 = (rblk & 1023) >> 4;
#pragma unroll
  for (int ct=0; ct<4; ++ct) {
    const int ctg = (cbase>>4) + w*4 + ct;
    const float bv = bias[ctg*16 + li];
#pragma unroll
    for (int rt=0; rt<4; ++rt) {
      f16x4 o;
#pragma unroll
      for (int i=0;i<4;++i) o[i] = (f16)(acc[rt][ct][i] + bv);
      *(f16x4*)(P + ((size_t)((bblk0 + rt)*T + t)*64 + ctg)*256 + l*4) = o;
    }
  }
}

// ================= fused recurrent kernel: encoder(5) then decoder(25) ======
// 64 blocks x 16 rows, 512 threads (8 waves). wave w owns h-cols [w*32,+32):
// ctg = q*16 + w*2 + j -> gate quadruples lane-local.
// acc C-init from fragment-order preg (x@Wih + biases pre-folded);
// single Whh weight stream per step (L2-resident).
__global__ __launch_bounds__(512) void k_rnn(
    const f16* __restrict__ pregE,   // [b_blk][5][64][64][4]
    const f16* __restrict__ pregD,   // [b_blk][25][64][64][4]
    const f16* __restrict__ Whh_e_p, const f16* __restrict__ Whh_d_p,
    const float* __restrict__ W3e, const float* __restrict__ W3d,
    const float* __restrict__ enc_pos, const float* __restrict__ dec_pos,
    const float* __restrict__ W2Wo, const float* __restrict__ b2Wo,
    float* __restrict__ out)         // (B,25,3)
{
  __shared__ f16 hLDS[16*256];       // swizzled (16B slot ^= row&7)
  __shared__ float W3s[3*1024];
  __shared__ float posS[2][16][4];
  __shared__ float dpart[8][16][3];
  const int tid = threadIdx.x, l = tid & 63, w = tid >> 6;
  const int li = l & 15, hi = l >> 4;
  const int bblk = blockIdx.x, rb = bblk*16;

  for (int i=tid;i<3072;i+=512) W3s[i]=W3e[i];
  float c_st[2][4];
#pragma unroll
  for (int j=0;j<2;++j)
#pragma unroll
    for (int i=0;i<4;++i) c_st[j][i]=0.f;

  // ---------------- encoder ----------------
  for (int t=0;t<5;++t) {
    f16x4 pv[4][2];
#pragma unroll
    for (int q=0;q<4;++q)
#pragma unroll
      for (int j=0;j<2;++j)
        pv[q][j] = *(const f16x4*)(pregE + ((size_t)((bblk*5 + t)*64) + q*16 + w*2 + j)*256 + l*4);
    float pp[4][3];
#pragma unroll
    for (int i=0;i<4;++i) {
      int grow = rb + hi*4 + i;
      pp[i][0]=enc_pos[(grow*5+t)*3+0]; pp[i][1]=enc_pos[(grow*5+t)*3+1]; pp[i][2]=enc_pos[(grow*5+t)*3+2];
    }
    f32x4 acc[4][2];
#pragma unroll
    for (int q=0;q<4;++q)
#pragma unroll
      for (int j=0;j<2;++j)
        acc[q][j] = (f32x4){(float)pv[q][j][0],(float)pv[q][j][1],(float)pv[q][j][2],(float)pv[q][j][3]};
    __syncthreads();               // A: prev-step hLDS writes (and t=0 W3s) visible
    if (t > 0) {
#pragma unroll
      for (int kf=0;kf<8;++kf) {
        f16x8 ah = *(f16x8*)&hLDS[li*256 + (((kf*4)+hi) ^ (li&7))*8];
#pragma unroll
        for (int q=0;q<4;++q)
#pragma unroll
          for (int j=0;j<2;++j) {
            int ctg = q*16 + w*2 + j;
            f16x8 bh = *(const f16x8*)(Whh_e_p + ((size_t)(kf*64+ctg)*64 + l)*8);
            acc[q][j] = MFMA16(ah, bh, acc[q][j]);
          }
      }
    }
    __syncthreads();               // B: hLDS reads done -> safe to rewrite
#pragma unroll
    for (int i=0;i<4;++i) {
      int r = hi*4 + i;
#pragma unroll
      for (int j=0;j<2;++j) {
        int hc = w*32 + j*16 + li;
        float gq[4];
#pragma unroll
        for (int q=0;q<4;++q) {
          int gc = q*256 + hc;
          gq[q] = acc[q][j][i] + pp[i][0]*W3s[gc] + pp[i][1]*W3s[1024+gc] + pp[i][2]*W3s[2048+gc];
        }
        float cn = sigm(gq[1])*c_st[j][i] + sigm(gq[0])*tanhf(gq[2]);
        c_st[j][i] = cn;
        float h = sigm(gq[3])*tanhf(cn);
        hLDS[r*256 + (((hc>>3) ^ (r&7))<<3) + (hc&7)] = (f16)h;
      }
    }
  }

  // ---------------- switch to decoder constants ----------------
  __syncthreads();                 // encoder gate-phase W3s reads done
  for (int i=tid;i<3072;i+=512) W3s[i]=W3d[i];
  float w2r[2][3];
#pragma unroll
  for (int j=0;j<2;++j) {
    int hc = w*32 + j*16 + li;
    w2r[j][0]=W2Wo[hc*3+0]; w2r[j][1]=W2Wo[hc*3+1]; w2r[j][2]=W2Wo[hc*3+2];
  }
  if (tid < 48) { int r=tid/3, k=tid-3*(tid/3); posS[0][r][k] = dec_pos[(size_t)(rb+r)*3 + k]; }
  const float b2w0 = b2Wo[0], b2w1 = b2Wo[1], b2w2 = b2Wo[2];

  // ---------------- decoder ----------------
  int cur = 0;
  for (int t=0;t<25;++t) {
    f16x4 pv[4][2];
#pragma unroll
    for (int q=0;q<4;++q)
#pragma unroll
      for (int j=0;j<2;++j)
        pv[q][j] = *(const f16x4*)(pregD + ((size_t)((bblk*25 + t)*64) + q*16 + w*2 + j)*256 + l*4);
    f32x4 acc[4][2];
#pragma unroll
    for (int q=0;q<4;++q)
#pragma unroll
      for (int j=0;j<2;++j)
        acc[q][j] = (f32x4){(float)pv[q][j][0],(float)pv[q][j][1],(float)pv[q][j][2],(float)pv[q][j][3]};
    __syncthreads();               // A: prev hLDS/posS writes (and W3s swap) visible
#pragma unroll
    for (int kf=0;kf<8;++kf) {
      f16x8 ah = *(f16x8*)&hLDS[li*256 + (((kf*4)+hi) ^ (li&7))*8];
#pragma unroll
      for (int q=0;q<4;++q)
#pragma unroll
        for (int j=0;j<2;++j) {
          int ctg = q*16 + w*2 + j;
          f16x8 bh = *(const f16x8*)(Whh_d_p + ((size_t)(kf*64+ctg)*64 + l)*8);
          acc[q][j] = MFMA16(ah, bh, acc[q][j]);
        }
    }
    __syncthreads();               // B: hLDS reads done
    float dpar[4][3];
#pragma unroll
    for (int i=0;i<4;++i){ dpar[i][0]=0.f; dpar[i][1]=0.f; dpar[i][2]=0.f; }
#pragma unroll
    for (int i=0;i<4;++i) {
      int r = hi*4 + i;
      float p0 = posS[cur][r][0], p1 = posS[cur][r][1], p2 = posS[cur][r][2];
#pragma unroll
      for (int j=0;j<2;++j) {
        int hc = w*32 + j*16 + li;
        float gq[4];
#pragma unroll
        for (int q=0;q<4;++q) {
          int gc = q*256 + hc;
          gq[q] = acc[q][j][i] + p0*W3s[gc] + p1*W3s[1024+gc] + p2*W3s[2048+gc];
        }
        float cn = sigm(gq[1])*c_st[j][i] + sigm(gq[0])*tanhf(gq[2]);
        c_st[j][i] = cn;
        float h = sigm(gq[3])*tanhf(cn);
        hLDS[r*256 + (((hc>>3) ^ (r&7))<<3) + (hc&7)] = (f16)h;
        dpar[i][0] += h*w2r[j][0];
        dpar[i][1] += h*w2r[j][1];
        dpar[i][2] += h*w2r[j][2];
      }
    }
#pragma unroll
    for (int m=1;m<16;m<<=1)
#pragma unroll
      for (int i=0;i<4;++i) {
        dpar[i][0] += __shfl_xor(dpar[i][0], m);
        dpar[i][1] += __shfl_xor(dpar[i][1], m);
        dpar[i][2] += __shfl_xor(dpar[i][2], m);
      }
    if (li==0) {
#pragma unroll
      for (int i=0;i<4;++i) {
        int r = hi*4 + i;
        dpart[w][r][0]=dpar[i][0]; dpart[w][r][1]=dpar[i][1]; dpart[w][r][2]=dpar[i][2];
      }
    }
    __syncthreads();               // C: dpart visible
    if (tid < 16) {
      int r = tid;
      float d0=b2w0, d1=b2w1, d2=b2w2;
#pragma unroll
      for (int ww=0;ww<8;++ww){ d0+=dpart[ww][r][0]; d1+=dpart[ww][r][1]; d2+=dpart[ww][r][2]; }
      float p0 = posS[cur][r][0]+d0, p1 = posS[cur][r][1]+d1, p2 = posS[cur][r][2]+d2;
      float inv = 1.0f/sqrtf(p0*p0+p1*p1+p2*p2);
      p0*=inv; p1*=inv; p2*=inv;
      posS[cur^1][r][0]=p0; posS[cur^1][r][1]=p1; posS[cur^1][r][2]=p2;
      float* o = out + (size_t)(rb+r)*75 + t*3;
      o[0]=p0; o[1]=p1; o[2]=p2;
    }
    cur ^= 1;
    // next iteration's barrier A orders posS/hLDS for readers
  }
}

// ================= launch =================
extern "C" void kernel_launch(void* const* d_in, const int* in_sizes, int n_in,
                              void* d_out, int out_size, void* d_ws, size_t ws_size,
                              hipStream_t stream)
{
  const float* enc_pos = (const float*)d_in[0];
  const float* enc_sal = (const float*)d_in[1];
  const float* dec_pos = (const float*)d_in[2];
  const float* dec_sal = (const float*)d_in[3];
  const float* Wpe  = (const float*)d_in[4];
  const float* bpe  = (const float*)d_in[5];
  const float* Wse  = (const float*)d_in[6];
  const float* bse  = (const float*)d_in[7];
  const float* Wih_e= (const float*)d_in[8];
  const float* Whh_e= (const float*)d_in[9];
  const float* bih_e= (const float*)d_in[10];
  const float* bhh_e= (const float*)d_in[11];
  const float* Wih_d= (const float*)d_in[12];
  const float* Whh_d= (const float*)d_in[13];
  const float* bih_d= (const float*)d_in[14];
  const float* bhh_d= (const float*)d_in[15];
  const float* Wpd  = (const float*)d_in[16];
  const float* bpd  = (const float*)d_in[17];
  const float* Wsd  = (const float*)d_in[18];
  const float* bsd  = (const float*)d_in[19];
  const float* W2   = (const float*)d_in[20];
  const float* b2   = (const float*)d_in[21];
  const float* Wo   = (const float*)d_in[22];
  const float* bo   = (const float*)d_in[23];

  char* ws = (char*)d_ws;
  f16* pWse   = (f16*)(ws + OFF_WSE_P);
  f16* pWsd   = (f16*)(ws + OFF_WSD_P);
  f16* pWih_e = (f16*)(ws + OFF_WIHE_P);
  f16* pWih_d = (f16*)(ws + OFF_WIHD_P);
  f16* pWhh_e = (f16*)(ws + OFF_WHHE_P);
  f16* pWhh_d = (f16*)(ws + OFF_WHHD_P);
  float* W3e  = (float*)(ws + OFF_W3E);
  float* W3d  = (float*)(ws + OFF_W3D);
  float* W2WoP= (float*)(ws + OFF_W2WO);
  float* biasE= (float*)(ws + OFF_BIASE);
  float* biasD= (float*)(ws + OFF_BIASD);
  float* b2WoP= (float*)(ws + OFF_B2WO);
  f16* sal_e  = (f16*)(ws + OFF_SALE);
  f16* sal_d  = (f16*)(ws + OFF_SALD);
  f16* pregE  = (f16*)(ws + OFF_PREGE);
  f16* pregD  = (f16*)(ws + OFF_PREGD);
  float* out  = (float*)d_out;

  hipLaunchKernelGGL(k_prep, dim3(2570), dim3(256), 0, stream,
                     Wse, Wsd, Wih_e, Wih_d, Whh_e, Whh_d,
                     pWse, pWsd, pWih_e, pWih_d, pWhh_e, pWhh_d,
                     Wpe, bpe, bih_e, bhh_e, Wpd, bpd, bih_d, bhh_d,
                     W2, b2, Wo, bo,
                     W3e, W3d, biasE, biasD, W2WoP, b2WoP);
  // sal projections: enc tiles [0,40), dec tiles [40,240)
  hipLaunchKernelGGL(k_gemm_big, dim3(240), dim3(512), 0, stream,
                     enc_sal, pWse, bse, sal_e, 40,
                     dec_sal, pWsd, bsd, sal_d);
  // pre-gate GEMM (t-major rows, fragment-order output, bias folded)
  hipLaunchKernelGGL(k_pregate, dim3(480,4), dim3(256), 0, stream,
                     sal_e, pWih_e, biasE, pregE, 80, 5,
                     sal_d, pWih_d, biasD, pregD, 25);
  // fused encoder+decoder recurrence
  hipLaunchKernelGGL(k_rnn, dim3(64), dim3(512), 0, stream,
                     pregE, pregD, pWhh_e, pWhh_d,
                     W3e, W3d, enc_pos, dec_pos,
                     W2WoP, b2WoP, out);
}